// Round 4
// baseline (378.436 us; speedup 1.0000x reference)
//
#include <hip/hip_runtime.h>
#include <hip/hip_bf16.h>
#include <math.h>

// Problem constants
constexpr int B = 8, S = 512, T = 256, D = 768, H = 12, HID = 3072;
constexpr int V = 50257, O = 64, HD = 64;

typedef short bf16x8 __attribute__((ext_vector_type(8)));
typedef float f32x4 __attribute__((ext_vector_type(4)));

__device__ __forceinline__ float b2f(unsigned short u) {
  union { float f; unsigned v; } x; x.v = ((unsigned)u) << 16; return x.f;
}
__device__ __forceinline__ unsigned short f2b(float f) {
  __hip_bfloat16 h = __float2bfloat16(f);
  return *(unsigned short*)&h;
}

__device__ __forceinline__ void async16(const void* g, void* l) {
  __builtin_amdgcn_global_load_lds(
      (const __attribute__((address_space(1))) void*)g,
      (__attribute__((address_space(3))) void*)l, 16, 0, 0);
}

// ---------------------------------------------------------------------------
// Zero-fill (float4 grid-stride). Replaces hipMemsetAsync, whose rocclr fill
// kernel was measured writing 4x the buffer size (1.6 GB for 412 MB).
// ---------------------------------------------------------------------------
__global__ void zero_out_kernel(float4* __restrict__ out, long long n4) {
  long long i = (long long)blockIdx.x * blockDim.x + threadIdx.x;
  const long long stride = (long long)gridDim.x * blockDim.x;
  const float4 z = make_float4(0.f, 0.f, 0.f, 0.f);
  for (; i < n4; i += stride) out[i] = z;
}

// ---------------------------------------------------------------------------
// fp32 -> bf16 conversion (8 elems/thread, n % 8 == 0)
// ---------------------------------------------------------------------------
__global__ void cvt_f32_bf16(const float* __restrict__ in,
                             __hip_bfloat16* __restrict__ out, int n) {
  int i = (blockIdx.x * blockDim.x + threadIdx.x) * 8;
  if (i + 8 > n) return;
  float4 v0 = *(const float4*)&in[i];
  float4 v1 = *(const float4*)&in[i + 4];
  ushort4 o0, o1;
  o0.x = f2b(v0.x); o0.y = f2b(v0.y); o0.z = f2b(v0.z); o0.w = f2b(v0.w);
  o1.x = f2b(v1.x); o1.y = f2b(v1.y); o1.z = f2b(v1.z); o1.w = f2b(v1.w);
  *(ushort4*)&out[i] = o0;
  *(ushort4*)&out[i + 4] = o1;
}

// ---------------------------------------------------------------------------
// bf16 MFMA GEMM: C[M,N] = A[M,K] @ W[N,K]^T + bias, optional ReLU.
// BM=128, BN in {64,128}, BK=32. 256 threads = 4 waves (2x2).
// TRANSV: write Cb transposed as vt[(r/512)*768 + c][r%512] (V for attention).
// ---------------------------------------------------------------------------
template <int BN, bool RELU, bool TRANSV>
__global__ __launch_bounds__(256) void gemm_mfma_kernel(
    const __hip_bfloat16* __restrict__ A, const __hip_bfloat16* __restrict__ W,
    const float* __restrict__ bias, float* __restrict__ Cf,
    __hip_bfloat16* __restrict__ Cb, int M, int N, int K) {
  constexpr int BM = 128, BK = 32;
  constexpr int WTN = BN / 2;      // wave tile N: 64 or 32
  constexpr int NFRAG = WTN / 16;  // 4 or 2
  __shared__ __hip_bfloat16 Als[BM * BK];
  __shared__ __hip_bfloat16 Bls[BN * BK];
  const int tid = threadIdx.x;
  const int lane = tid & 63, wid = tid >> 6;
  const int wm = wid >> 1, wn = wid & 1;
  const int row0 = blockIdx.y * BM, col0 = blockIdx.x * BN;
  const int lr = lane & 15;          // frag row/col
  const int ko = (lane >> 4) * 8;    // frag k offset (elems)

  f32x4 acc[4][NFRAG] = {};

  for (int k0 = 0; k0 < K; k0 += BK) {
#pragma unroll
    for (int c = 0; c < 2; ++c) {
      int j = tid + c * 256;
      int r = j >> 2, col = (j & 3) * 8;
      async16(&A[(size_t)(row0 + r) * K + k0 + col], (void*)&Als[j * 8]);
    }
#pragma unroll
    for (int c = 0; c < BN / 64; ++c) {
      int j = tid + c * 256;
      int r = j >> 2, col = (j & 3) * 8;
      async16(&W[(size_t)(col0 + r) * K + k0 + col], (void*)&Bls[j * 8]);
    }
    __syncthreads();

    bf16x8 af[4], bfr[NFRAG];
#pragma unroll
    for (int mi = 0; mi < 4; ++mi)
      af[mi] = *(const bf16x8*)&Als[(wm * 64 + mi * 16 + lr) * BK + ko];
#pragma unroll
    for (int ni = 0; ni < NFRAG; ++ni)
      bfr[ni] = *(const bf16x8*)&Bls[(wn * WTN + ni * 16 + lr) * BK + ko];
#pragma unroll
    for (int mi = 0; mi < 4; ++mi)
#pragma unroll
      for (int ni = 0; ni < NFRAG; ++ni)
        acc[mi][ni] = __builtin_amdgcn_mfma_f32_16x16x32_bf16(
            af[mi], bfr[ni], acc[mi][ni], 0, 0, 0);
    __syncthreads();
  }

#pragma unroll
  for (int mi = 0; mi < 4; ++mi) {
    int rbase = row0 + wm * 64 + mi * 16 + (lane >> 4) * 4;
#pragma unroll
    for (int ni = 0; ni < NFRAG; ++ni) {
      int c = col0 + wn * WTN + ni * 16 + lr;
      float bv = bias[c];
#pragma unroll
      for (int r = 0; r < 4; ++r) {
        float val = acc[mi][ni][r] + bv;
        if (RELU) val = fmaxf(val, 0.f);
        int rr = rbase + r;
        if (TRANSV) {
          // vt[((rr/512)*768 + c)][rr%512]
          size_t idx = (((size_t)(rr >> 9) * D + c) << 9) | (size_t)(rr & 511);
          Cb[idx] = __float2bfloat16(val);
        } else {
          if (Cf) Cf[(size_t)rr * N + c] = val;
          if (Cb) Cb[(size_t)rr * N + c] = __float2bfloat16(val);
        }
      }
    }
  }
}

// ---------------------------------------------------------------------------
// Row softmax over O=64 (one wave per row)
// ---------------------------------------------------------------------------
__global__ void softmax64_kernel(const float* __restrict__ logits,
                                 float* __restrict__ probs, int rows) {
  int row = blockIdx.x * (blockDim.x >> 6) + (threadIdx.x >> 6);
  int lane = threadIdx.x & 63;
  if (row >= rows) return;
  float x = logits[(size_t)row * 64 + lane];
  float m = x;
#pragma unroll
  for (int o = 32; o > 0; o >>= 1) m = fmaxf(m, __shfl_xor(m, o));
  float e = __expf(x - m);
  float ssum = e;
#pragma unroll
  for (int o = 32; o > 0; o >>= 1) ssum += __shfl_xor(ssum, o);
  probs[(size_t)row * 64 + lane] = e / ssum;
}

// ---------------------------------------------------------------------------
// Attention v3 (MFMA): one block (256 thr = 4 waves) per (b, h, 32-t tile).
// q,k normal [row][D] bf16; vt transposed [b][h][d][s] bf16.
// QK^T and PV via mfma_f32_16x16x32_bf16. Scores/P in LDS bf16 [32][520].
// K/Vt staged via global_load_lds with pre-swizzled source (slot ^= row&7).
// P written to global Pg[b][h][t][s] (head-mean done in scatter).
// ---------------------------------------------------------------------------
__global__ __launch_bounds__(256) void attention3_kernel(
    const __hip_bfloat16* __restrict__ q, const __hip_bfloat16* __restrict__ k,
    const __hip_bfloat16* __restrict__ vt, const unsigned char* __restrict__ mask,
    __hip_bfloat16* __restrict__ ctx, __hip_bfloat16* __restrict__ Pg) {
  constexpr int TB = 32;
  constexpr int SCP = 520;  // sc row stride (elems)
  __shared__ __hip_bfloat16 Qls[TB * 64];     // 4 KB, swizzled
  __shared__ __hip_bfloat16 KVls[128 * 64];   // 16 KB, K chunk or Vt chunk
  __shared__ __hip_bfloat16 sc[TB * SCP];     // 32.5 KB scores/P
  const int tid = threadIdx.x;
  const int lane = tid & 63, w = tid >> 6;
  const int lr = lane & 15, lg = lane >> 4;
  const int bid = blockIdx.x;
  const int tile = bid & 7;            // T/32 = 8
  const int h = (bid >> 3) % H;
  const int b = bid / (8 * H);
  const int t0 = tile * TB;

  // stage Q (32x64): 256 chunks of 16B, source slot pre-swizzled
  {
    int r = tid >> 3, slot = tid & 7;
    int g = slot ^ (r & 7);
    async16(&q[((size_t)(b * T + t0 + r)) * D + h * 64 + g * 8],
            (void*)&Qls[tid * 8]);
  }

  // ---- QK^T: 4 chunks of 128 s ----
  for (int ch = 0; ch < 4; ++ch) {
    const int s0 = ch * 128;
#pragma unroll
    for (int it = 0; it < 4; ++it) {
      int c = tid + it * 256;
      int r = c >> 3, slot = c & 7;
      int g = slot ^ (r & 7);
      async16(&k[((size_t)(b * S + s0 + r)) * D + h * 64 + g * 8],
              (void*)&KVls[c * 8]);
    }
    __syncthreads();
    f32x4 acc[2][2] = {};
#pragma unroll
    for (int ks = 0; ks < 2; ++ks) {
      bf16x8 af[2], bfr[2];
#pragma unroll
      for (int mi = 0; mi < 2; ++mi) {
        int row = mi * 16 + lr;
        int slot = (4 * ks + lg) ^ (row & 7);
        af[mi] = *(const bf16x8*)&Qls[row * 64 + slot * 8];
      }
#pragma unroll
      for (int ni = 0; ni < 2; ++ni) {
        int row = w * 32 + ni * 16 + lr;
        int slot = (4 * ks + lg) ^ (row & 7);
        bfr[ni] = *(const bf16x8*)&KVls[row * 64 + slot * 8];
      }
#pragma unroll
      for (int mi = 0; mi < 2; ++mi)
#pragma unroll
        for (int ni = 0; ni < 2; ++ni)
          acc[mi][ni] = __builtin_amdgcn_mfma_f32_16x16x32_bf16(
              af[mi], bfr[ni], acc[mi][ni], 0, 0, 0);
    }
    // scale + mask + store scores (bf16) to sc
#pragma unroll
    for (int ni = 0; ni < 2; ++ni) {
      int s_local = w * 32 + ni * 16 + lr;
      bool msk = mask[b * S + s0 + s_local];
#pragma unroll
      for (int mi = 0; mi < 2; ++mi) {
        int trow = mi * 16 + lg * 4;
#pragma unroll
        for (int rg = 0; rg < 4; ++rg) {
          float val = msk ? -INFINITY : acc[mi][ni][rg] * 0.125f;
          sc[(trow + rg) * SCP + s0 + s_local] = __float2bfloat16(val);
        }
      }
    }
    __syncthreads();
  }

  // ---- softmax: wave w handles rows w*8 .. w*8+7 ----
  unsigned short* scu = (unsigned short*)sc;
  unsigned short* pgu = (unsigned short*)Pg;
#pragma unroll
  for (int i = 0; i < 8; ++i) {
    int r = w * 8 + i;
    float x[8];
    float m = -INFINITY;
#pragma unroll
    for (int j = 0; j < 8; ++j) {
      x[j] = b2f(scu[r * SCP + j * 64 + lane]);
      m = fmaxf(m, x[j]);
    }
#pragma unroll
    for (int o = 32; o > 0; o >>= 1) m = fmaxf(m, __shfl_xor(m, o));
    float ssum = 0.f;
#pragma unroll
    for (int j = 0; j < 8; ++j) { x[j] = __expf(x[j] - m); ssum += x[j]; }
#pragma unroll
    for (int o = 32; o > 0; o >>= 1) ssum += __shfl_xor(ssum, o);
    float inv = 1.f / ssum;
#pragma unroll
    for (int j = 0; j < 8; ++j) {
      unsigned short pb = f2b(x[j] * inv);
      scu[r * SCP + j * 64 + lane] = pb;
      pgu[(((size_t)(b * H + h)) * T + t0 + r) * S + j * 64 + lane] = pb;
    }
  }
  __syncthreads();

  // ---- PV: wave w owns d range [w*16, w*16+16) ----
  f32x4 accp[2] = {};
  for (int ch = 0; ch < 4; ++ch) {
    const int s0 = ch * 128;
#pragma unroll
    for (int it = 0; it < 4; ++it) {
      int c = tid + it * 256;
      int d = c >> 4, slot = c & 15;
      int g = slot ^ (d & 7);
      async16(&vt[(((size_t)(b * H + h)) * 64 + d) * S + s0 + g * 8],
              (void*)&KVls[c * 8]);
    }
    __syncthreads();
#pragma unroll
    for (int ks = 0; ks < 4; ++ks) {
      bf16x8 bfr;
      {
        int brow = w * 16 + lr;
        int slot = (4 * ks + lg) ^ (brow & 7);
        bfr = *(const bf16x8*)&KVls[brow * 128 + slot * 8];
      }
#pragma unroll
      for (int mi = 0; mi < 2; ++mi) {
        int prow = mi * 16 + lr;
        bf16x8 af = *(const bf16x8*)&sc[prow * SCP + s0 + ks * 32 + lg * 8];
        accp[mi] = __builtin_amdgcn_mfma_f32_16x16x32_bf16(af, bfr, accp[mi], 0, 0, 0);
      }
    }
    __syncthreads();
  }
  // epilogue: ctx[b*T + t][h*64 + d]
#pragma unroll
  for (int mi = 0; mi < 2; ++mi) {
    int trow = mi * 16 + lg * 4;
#pragma unroll
    for (int rg = 0; rg < 4; ++rg) {
      ctx[((size_t)(b * T + t0 + trow + rg)) * D + h * 64 + w * 16 + lr] =
          __float2bfloat16(accp[mi][rg]);
    }
  }
}

// ---------------------------------------------------------------------------
// Copy head: sigmoid(context_out @ copy_w + copy_b), one wave per row
// ---------------------------------------------------------------------------
__global__ void copy_head_kernel(const float* __restrict__ co,
                                 const float* __restrict__ w,
                                 const float* __restrict__ bptr,
                                 float* __restrict__ cp, int rows) {
  int row = blockIdx.x * (blockDim.x >> 6) + (threadIdx.x >> 6);
  int lane = threadIdx.x & 63;
  if (row >= rows) return;
  float acc = 0.f;
#pragma unroll
  for (int d = lane; d < D; d += 64) acc += co[(size_t)row * D + d] * w[d];
#pragma unroll
  for (int o = 32; o > 0; o >>= 1) acc += __shfl_xor(acc, o);
  if (lane == 0) cp[row] = 1.f / (1.f + __expf(-(acc + bptr[0])));
}

// ---------------------------------------------------------------------------
// Scatter: head-mean of Pg + copy gate, atomically into out (pre-zeroed)
// ---------------------------------------------------------------------------
__global__ void scatter2_kernel(const int* __restrict__ src,
                                const int* __restrict__ onto,
                                const __hip_bfloat16* __restrict__ Pg,
                                const float* __restrict__ op,
                                const float* __restrict__ cp,
                                float* __restrict__ out) {
  long long i = (long long)blockIdx.x * blockDim.x + threadIdx.x;
  const long long nsrc = (long long)B * T * S;
  const long long nonto = (long long)B * T * O;
  if (i < nsrc) {
    int s = (int)(i & (S - 1));
    int bt = (int)(i >> 9);
    int b = bt >> 8;
    int t = bt & (T - 1);
    const unsigned short* pg = (const unsigned short*)Pg;
    float sum = 0.f;
#pragma unroll
    for (int h = 0; h < H; ++h)
      sum += b2f(pg[(((size_t)(b * H + h)) * T + t) * S + s]);
    float val = sum * (1.0f / (float)H) * cp[bt];
    atomicAdd(&out[(size_t)bt * V + src[b * S + s]], val);
  } else if (i < nsrc + nonto) {
    long long j = i - nsrc;
    int o = (int)(j % O);
    long long bt = j / O;
    float val = op[j] * (1.f - cp[bt]);
    atomicAdd(&out[bt * V + onto[o]], val);
  }
}

// ---------------------------------------------------------------------------
extern "C" void kernel_launch(void* const* d_in, const int* in_sizes, int n_in,
                              void* d_out, int out_size, void* d_ws, size_t ws_size,
                              hipStream_t stream) {
  const int* src_ids = (const int*)d_in[0];
  const float* enc = (const float*)d_in[1];
  const unsigned char* mask = (const unsigned char*)d_in[2];
  const float* dec = (const float*)d_in[3];
  const int* onto_ids = (const int*)d_in[4];
  const float* Wq = (const float*)d_in[5];
  const float* bq = (const float*)d_in[6];
  const float* Wk = (const float*)d_in[7];
  const float* bk = (const float*)d_in[8];
  const float* Wv = (const float*)d_in[9];
  const float* bv = (const float*)d_in[10];
  const float* Wo = (const float*)d_in[11];
  const float* bo = (const float*)d_in[12];
  const float* copy_w = (const float*)d_in[13];
  const float* copy_b = (const float*)d_in[14];
  const float* W1 = (const float*)d_in[15];
  const float* b1 = (const float*)d_in[16];
  const float* W2 = (const float*)d_in[17];
  const float* b2 = (const float*)d_in[18];

  const int MT = B * T;   // 2048
  const int MS = B * S;   // 4096

  // bf16 workspace
  __hip_bfloat16* wb = (__hip_bfloat16*)d_ws;
  __hip_bfloat16* qb16 = wb;    wb += (size_t)MT * D;
  __hip_bfloat16* kb16 = wb;    wb += (size_t)MS * D;
  __hip_bfloat16* vt = wb;      wb += (size_t)MS * D;   // [b][h][d][s]
  __hip_bfloat16* ctxb16 = wb;  wb += (size_t)MT * D;
  __hip_bfloat16* W2b = wb;     wb += (size_t)O * HID;
  __hip_bfloat16* Wqb = wb;     wb += (size_t)D * D;
  __hip_bfloat16* Wkb = wb;     wb += (size_t)D * D;
  __hip_bfloat16* Wvb = wb;     wb += (size_t)D * D;
  __hip_bfloat16* Wob = wb;     wb += (size_t)D * D;
  // alias region: Pg [B,H,T,S] overlays decb/encb/W1b/hb16 — all consumers
  // of the latter finish before attention3 writes Pg.
  __hip_bfloat16* Pg = wb;
  __hip_bfloat16* decb = wb;    wb += (size_t)MT * D;
  __hip_bfloat16* encb = wb;    wb += (size_t)MS * D;
  __hip_bfloat16* W1b = wb;     wb += (size_t)HID * D;
  __hip_bfloat16* hb16 = wb;    wb += (size_t)MT * HID;
  // fp32 workspace
  float* wf = (float*)wb;
  float* logits = wf;           wf += (size_t)MT * O;
  float* ontop = wf;            wf += (size_t)MT * O;
  float* ctxout = wf;           wf += (size_t)MT * D;
  float* cp = wf;               wf += (size_t)MT;

  float* out = (float*)d_out;

  // Zero output with our own float4 kernel (rocclr fill wrote 4x traffic).
  {
    long long n4 = (long long)B * T * V / 4;  // V*B*T divisible by 4
    zero_out_kernel<<<2048, 256, 0, stream>>>((float4*)out, n4);
  }

  auto cvt = [&](const float* s, __hip_bfloat16* dst, int n) {
    cvt_f32_bf16<<<(n / 8 + 255) / 256, 256, 0, stream>>>(s, dst, n);
  };
  cvt(dec, decb, MT * D);
  cvt(enc, encb, MS * D);
  cvt(W1, W1b, HID * D);
  cvt(W2, W2b, O * HID);
  cvt(Wq, Wqb, D * D);
  cvt(Wk, Wkb, D * D);
  cvt(Wv, Wvb, D * D);
  cvt(Wo, Wob, D * D);

  // Projections (V written transposed for attention)
  gemm_mfma_kernel<128, false, false><<<dim3(D / 128, MT / 128), 256, 0, stream>>>(
      decb, Wqb, bq, nullptr, qb16, MT, D, D);
  gemm_mfma_kernel<128, false, false><<<dim3(D / 128, MS / 128), 256, 0, stream>>>(
      encb, Wkb, bk, nullptr, kb16, MS, D, D);
  gemm_mfma_kernel<128, false, true><<<dim3(D / 128, MS / 128), 256, 0, stream>>>(
      encb, Wvb, bv, nullptr, vt, MS, D, D);

  // Generator FFN
  gemm_mfma_kernel<128, true, false><<<dim3(HID / 128, MT / 128), 256, 0, stream>>>(
      decb, W1b, b1, nullptr, hb16, MT, HID, D);
  gemm_mfma_kernel<64, false, false><<<dim3(1, MT / 128), 256, 0, stream>>>(
      hb16, W2b, b2, logits, nullptr, MT, O, HID);
  softmax64_kernel<<<MT / 4, 256, 0, stream>>>(logits, ontop, MT);

  // Attention
  attention3_kernel<<<B * H * (T / 32), 256, 0, stream>>>(
      qb16, kb16, vt, mask, ctxb16, Pg);

  // Output projection + copy head
  gemm_mfma_kernel<128, false, false><<<dim3(D / 128, MT / 128), 256, 0, stream>>>(
      ctxb16, Wob, bo, ctxout, nullptr, MT, D, D);
  copy_head_kernel<<<MT / 4, 256, 0, stream>>>(ctxout, copy_w, copy_b, cp, MT);

  // Scatter
  long long total = (long long)B * T * (S + O);
  int nblk = (int)((total + 255) / 256);
  scatter2_kernel<<<nblk, 256, 0, stream>>>(src_ids, onto_ids, Pg, ontop, cp, out);
}

// Round 6
// 354.189 us; speedup vs baseline: 1.0685x; 1.0685x over previous
//
#include <hip/hip_runtime.h>
#include <hip/hip_bf16.h>
#include <math.h>

// Problem constants
constexpr int B = 8, S = 512, T = 256, D = 768, H = 12, HID = 3072;
constexpr int V = 50257, O = 64, HD = 64;

typedef short bf16x8 __attribute__((ext_vector_type(8)));
typedef float f32x4 __attribute__((ext_vector_type(4)));

__device__ __forceinline__ float b2f(unsigned short u) {
  union { float f; unsigned v; } x; x.v = ((unsigned)u) << 16; return x.f;
}
__device__ __forceinline__ unsigned short f2b(float f) {
  __hip_bfloat16 h = __float2bfloat16(f);
  return *(unsigned short*)&h;
}

__device__ __forceinline__ void async16(const void* g, void* l) {
  __builtin_amdgcn_global_load_lds(
      (const __attribute__((address_space(1))) void*)g,
      (__attribute__((address_space(3))) void*)l, 16, 0, 0);
}

// ---------------------------------------------------------------------------
// Zero-fill (ext-vector float4 grid-stride, nontemporal)
// ---------------------------------------------------------------------------
__global__ void zero_out_kernel(f32x4* __restrict__ out, long long n4) {
  long long i = (long long)blockIdx.x * blockDim.x + threadIdx.x;
  const long long stride = (long long)gridDim.x * blockDim.x;
  const f32x4 z = {0.f, 0.f, 0.f, 0.f};
  for (; i < n4; i += stride) __builtin_nontemporal_store(z, &out[i]);
}

// ---------------------------------------------------------------------------
// Fused fp32->bf16 conversion of all 8 regions in one launch.
// Region table (in 8-elem chunks, compile-time):
//   dec -> decb | enc -> encb | W1 -> WA[0] | Wq -> WA[HID*D]
//   Wk -> WB[0] | Wv -> WB[D*D] | W2 -> W2b | Wo -> Wob
// ---------------------------------------------------------------------------
constexpr int CH0 = B * T * D / 8;            // dec
constexpr int CH1 = CH0 + B * S * D / 8;      // enc
constexpr int CH2 = CH1 + HID * D / 8;        // W1
constexpr int CH3 = CH2 + D * D / 8;          // Wq
constexpr int CH4 = CH3 + D * D / 8;          // Wk
constexpr int CH5 = CH4 + D * D / 8;          // Wv
constexpr int CH6 = CH5 + O * HID / 8;        // W2
constexpr int CH7 = CH6 + D * D / 8;          // Wo

__global__ void cvt_all_kernel(
    const float* __restrict__ dec, const float* __restrict__ enc,
    const float* __restrict__ W1, const float* __restrict__ Wq,
    const float* __restrict__ Wk, const float* __restrict__ Wv,
    const float* __restrict__ W2, const float* __restrict__ Wo,
    __hip_bfloat16* __restrict__ decb, __hip_bfloat16* __restrict__ encb,
    __hip_bfloat16* __restrict__ WA, __hip_bfloat16* __restrict__ WB,
    __hip_bfloat16* __restrict__ W2b, __hip_bfloat16* __restrict__ Wob) {
  int i = blockIdx.x * blockDim.x + threadIdx.x;
  const float* src;
  __hip_bfloat16* dst;
  int j;
  if (i < CH0)      { src = dec; dst = decb;                     j = i; }
  else if (i < CH1) { src = enc; dst = encb;                     j = i - CH0; }
  else if (i < CH2) { src = W1;  dst = WA;                       j = i - CH1; }
  else if (i < CH3) { src = Wq;  dst = WA + (size_t)HID * D;     j = i - CH2; }
  else if (i < CH4) { src = Wk;  dst = WB;                       j = i - CH3; }
  else if (i < CH5) { src = Wv;  dst = WB + (size_t)D * D;       j = i - CH4; }
  else if (i < CH6) { src = W2;  dst = W2b;                      j = i - CH5; }
  else if (i < CH7) { src = Wo;  dst = Wob;                      j = i - CH6; }
  else return;
  size_t e = (size_t)j * 8;
  float4 v0 = *(const float4*)&src[e];
  float4 v1 = *(const float4*)&src[e + 4];
  ushort4 o0, o1;
  o0.x = f2b(v0.x); o0.y = f2b(v0.y); o0.z = f2b(v0.z); o0.w = f2b(v0.w);
  o1.x = f2b(v1.x); o1.y = f2b(v1.y); o1.z = f2b(v1.z); o1.w = f2b(v1.w);
  *(ushort4*)&dst[e] = o0;
  *(ushort4*)&dst[e + 4] = o1;
}

// ---------------------------------------------------------------------------
// bf16 MFMA GEMM, fused epilogues.
// MODE 0: Cf[r*N+c] = acc + bias0[c]                     (fp32 out)
// MODE 1: c<HID -> out0=relu(acc+bias0[c]) [r*HID+c];  else out1[r*D+c-HID]
//         = acc + bias1[c-HID]                           (FFN1 + Q fused)
// MODE 2: c<D  -> out0[r*D+c] = acc+bias0[c];  else d=c-D:
//         out1[vt-transposed] = acc + bias1[d]           (K + V fused)
// BM=128, BN in {64,128}, BK=32, 256 threads = 4 waves.
// ---------------------------------------------------------------------------
template <int BN, int MODE>
__global__ __launch_bounds__(256) void gemm_mfma_kernel(
    const __hip_bfloat16* __restrict__ A, const __hip_bfloat16* __restrict__ W,
    const float* __restrict__ bias0, const float* __restrict__ bias1,
    float* __restrict__ Cf, __hip_bfloat16* __restrict__ out0,
    __hip_bfloat16* __restrict__ out1, int M, int N, int K) {
  constexpr int BM = 128, BK = 32;
  constexpr int WTN = BN / 2;
  constexpr int NFRAG = WTN / 16;
  __shared__ __hip_bfloat16 Als[BM * BK];
  __shared__ __hip_bfloat16 Bls[BN * BK];
  const int tid = threadIdx.x;
  const int lane = tid & 63, wid = tid >> 6;
  const int wm = wid >> 1, wn = wid & 1;
  const int row0 = blockIdx.y * BM, col0 = blockIdx.x * BN;
  const int lr = lane & 15;
  const int ko = (lane >> 4) * 8;

  f32x4 acc[4][NFRAG] = {};

  for (int k0 = 0; k0 < K; k0 += BK) {
#pragma unroll
    for (int c = 0; c < 2; ++c) {
      int j = tid + c * 256;
      int r = j >> 2, col = (j & 3) * 8;
      async16(&A[(size_t)(row0 + r) * K + k0 + col], (void*)&Als[j * 8]);
    }
#pragma unroll
    for (int c = 0; c < BN / 64; ++c) {
      int j = tid + c * 256;
      int r = j >> 2, col = (j & 3) * 8;
      async16(&W[(size_t)(col0 + r) * K + k0 + col], (void*)&Bls[j * 8]);
    }
    __syncthreads();

    bf16x8 af[4], bfr[NFRAG];
#pragma unroll
    for (int mi = 0; mi < 4; ++mi)
      af[mi] = *(const bf16x8*)&Als[(wm * 64 + mi * 16 + lr) * BK + ko];
#pragma unroll
    for (int ni = 0; ni < NFRAG; ++ni)
      bfr[ni] = *(const bf16x8*)&Bls[(wn * WTN + ni * 16 + lr) * BK + ko];
#pragma unroll
    for (int mi = 0; mi < 4; ++mi)
#pragma unroll
      for (int ni = 0; ni < NFRAG; ++ni)
        acc[mi][ni] = __builtin_amdgcn_mfma_f32_16x16x32_bf16(
            af[mi], bfr[ni], acc[mi][ni], 0, 0, 0);
    __syncthreads();
  }

#pragma unroll
  for (int mi = 0; mi < 4; ++mi) {
    int rbase = row0 + wm * 64 + mi * 16 + (lane >> 4) * 4;
#pragma unroll
    for (int ni = 0; ni < NFRAG; ++ni) {
      int c = col0 + wn * WTN + ni * 16 + lr;
#pragma unroll
      for (int r = 0; r < 4; ++r) {
        int rr = rbase + r;
        float a = acc[mi][ni][r];
        if constexpr (MODE == 0) {
          Cf[(size_t)rr * N + c] = a + bias0[c];
        } else if constexpr (MODE == 1) {
          if (c < HID) {
            out0[(size_t)rr * HID + c] = __float2bfloat16(fmaxf(a + bias0[c], 0.f));
          } else {
            out1[(size_t)rr * D + (c - HID)] = __float2bfloat16(a + bias1[c - HID]);
          }
        } else {
          if (c < D) {
            out0[(size_t)rr * D + c] = __float2bfloat16(a + bias0[c]);
          } else {
            int d = c - D;
            size_t idx = (((size_t)(rr >> 9) * D + d) << 9) | (size_t)(rr & 511);
            out1[idx] = __float2bfloat16(a + bias1[d]);
          }
        }
      }
    }
  }
}

// ---------------------------------------------------------------------------
// Row softmax over O=64 (one wave per row)
// ---------------------------------------------------------------------------
__global__ void softmax64_kernel(const float* __restrict__ logits,
                                 float* __restrict__ probs, int rows) {
  int row = blockIdx.x * (blockDim.x >> 6) + (threadIdx.x >> 6);
  int lane = threadIdx.x & 63;
  if (row >= rows) return;
  float x = logits[(size_t)row * 64 + lane];
  float m = x;
#pragma unroll
  for (int o = 32; o > 0; o >>= 1) m = fmaxf(m, __shfl_xor(m, o));
  float e = __expf(x - m);
  float ssum = e;
#pragma unroll
  for (int o = 32; o > 0; o >>= 1) ssum += __shfl_xor(ssum, o);
  probs[(size_t)row * 64 + lane] = e / ssum;
}

// ---------------------------------------------------------------------------
// Attention v3 (MFMA): one block (256 thr = 4 waves) per (b, h, 32-t tile).
// ---------------------------------------------------------------------------
__global__ __launch_bounds__(256) void attention3_kernel(
    const __hip_bfloat16* __restrict__ q, const __hip_bfloat16* __restrict__ k,
    const __hip_bfloat16* __restrict__ vt, const unsigned char* __restrict__ mask,
    __hip_bfloat16* __restrict__ ctx, __hip_bfloat16* __restrict__ Pg) {
  constexpr int TB = 32;
  constexpr int SCP = 520;
  __shared__ __hip_bfloat16 Qls[TB * 64];
  __shared__ __hip_bfloat16 KVls[128 * 64];
  __shared__ __hip_bfloat16 sc[TB * SCP];
  const int tid = threadIdx.x;
  const int lane = tid & 63, w = tid >> 6;
  const int lr = lane & 15, lg = lane >> 4;
  const int bid = blockIdx.x;
  const int tile = bid & 7;
  const int h = (bid >> 3) % H;
  const int b = bid / (8 * H);
  const int t0 = tile * TB;

  {
    int r = tid >> 3, slot = tid & 7;
    int g = slot ^ (r & 7);
    async16(&q[((size_t)(b * T + t0 + r)) * D + h * 64 + g * 8],
            (void*)&Qls[tid * 8]);
  }

  for (int ch = 0; ch < 4; ++ch) {
    const int s0 = ch * 128;
#pragma unroll
    for (int it = 0; it < 4; ++it) {
      int c = tid + it * 256;
      int r = c >> 3, slot = c & 7;
      int g = slot ^ (r & 7);
      async16(&k[((size_t)(b * S + s0 + r)) * D + h * 64 + g * 8],
              (void*)&KVls[c * 8]);
    }
    __syncthreads();
    f32x4 acc[2][2] = {};
#pragma unroll
    for (int ks = 0; ks < 2; ++ks) {
      bf16x8 af[2], bfr[2];
#pragma unroll
      for (int mi = 0; mi < 2; ++mi) {
        int row = mi * 16 + lr;
        int slot = (4 * ks + lg) ^ (row & 7);
        af[mi] = *(const bf16x8*)&Qls[row * 64 + slot * 8];
      }
#pragma unroll
      for (int ni = 0; ni < 2; ++ni) {
        int row = w * 32 + ni * 16 + lr;
        int slot = (4 * ks + lg) ^ (row & 7);
        bfr[ni] = *(const bf16x8*)&KVls[row * 64 + slot * 8];
      }
#pragma unroll
      for (int mi = 0; mi < 2; ++mi)
#pragma unroll
        for (int ni = 0; ni < 2; ++ni)
          acc[mi][ni] = __builtin_amdgcn_mfma_f32_16x16x32_bf16(
              af[mi], bfr[ni], acc[mi][ni], 0, 0, 0);
    }
#pragma unroll
    for (int ni = 0; ni < 2; ++ni) {
      int s_local = w * 32 + ni * 16 + lr;
      bool msk = mask[b * S + s0 + s_local];
#pragma unroll
      for (int mi = 0; mi < 2; ++mi) {
        int trow = mi * 16 + lg * 4;
#pragma unroll
        for (int rg = 0; rg < 4; ++rg) {
          float val = msk ? -INFINITY : acc[mi][ni][rg] * 0.125f;
          sc[(trow + rg) * SCP + s0 + s_local] = __float2bfloat16(val);
        }
      }
    }
    __syncthreads();
  }

  unsigned short* scu = (unsigned short*)sc;
  unsigned short* pgu = (unsigned short*)Pg;
#pragma unroll
  for (int i = 0; i < 8; ++i) {
    int r = w * 8 + i;
    float x[8];
    float m = -INFINITY;
#pragma unroll
    for (int j = 0; j < 8; ++j) {
      x[j] = b2f(scu[r * SCP + j * 64 + lane]);
      m = fmaxf(m, x[j]);
    }
#pragma unroll
    for (int o = 32; o > 0; o >>= 1) m = fmaxf(m, __shfl_xor(m, o));
    float ssum = 0.f;
#pragma unroll
    for (int j = 0; j < 8; ++j) { x[j] = __expf(x[j] - m); ssum += x[j]; }
#pragma unroll
    for (int o = 32; o > 0; o >>= 1) ssum += __shfl_xor(ssum, o);
    float inv = 1.f / ssum;
#pragma unroll
    for (int j = 0; j < 8; ++j) {
      unsigned short pb = f2b(x[j] * inv);
      scu[r * SCP + j * 64 + lane] = pb;
      pgu[(((size_t)(b * H + h)) * T + t0 + r) * S + j * 64 + lane] = pb;
    }
  }
  __syncthreads();

  f32x4 accp[2] = {};
  for (int ch = 0; ch < 4; ++ch) {
    const int s0 = ch * 128;
#pragma unroll
    for (int it = 0; it < 4; ++it) {
      int c = tid + it * 256;
      int d = c >> 4, slot = c & 15;
      int g = slot ^ (d & 7);
      async16(&vt[(((size_t)(b * H + h)) * 64 + d) * S + s0 + g * 8],
              (void*)&KVls[c * 8]);
    }
    __syncthreads();
#pragma unroll
    for (int ks = 0; ks < 4; ++ks) {
      bf16x8 bfr;
      {
        int brow = w * 16 + lr;
        int slot = (4 * ks + lg) ^ (brow & 7);
        bfr = *(const bf16x8*)&KVls[brow * 128 + slot * 8];
      }
#pragma unroll
      for (int mi = 0; mi < 2; ++mi) {
        int prow = mi * 16 + lr;
        bf16x8 af = *(const bf16x8*)&sc[prow * SCP + s0 + ks * 32 + lg * 8];
        accp[mi] = __builtin_amdgcn_mfma_f32_16x16x32_bf16(af, bfr, accp[mi], 0, 0, 0);
      }
    }
    __syncthreads();
  }
#pragma unroll
  for (int mi = 0; mi < 2; ++mi) {
    int trow = mi * 16 + lg * 4;
#pragma unroll
    for (int rg = 0; rg < 4; ++rg) {
      ctx[((size_t)(b * T + t0 + trow + rg)) * D + h * 64 + w * 16 + lr] =
          __float2bfloat16(accp[mi][rg]);
    }
  }
}

// ---------------------------------------------------------------------------
// Copy head
// ---------------------------------------------------------------------------
__global__ void copy_head_kernel(const float* __restrict__ co,
                                 const float* __restrict__ w,
                                 const float* __restrict__ bptr,
                                 float* __restrict__ cp, int rows) {
  int row = blockIdx.x * (blockDim.x >> 6) + (threadIdx.x >> 6);
  int lane = threadIdx.x & 63;
  if (row >= rows) return;
  float acc = 0.f;
#pragma unroll
  for (int d = lane; d < D; d += 64) acc += co[(size_t)row * D + d] * w[d];
#pragma unroll
  for (int o = 32; o > 0; o >>= 1) acc += __shfl_xor(acc, o);
  if (lane == 0) cp[row] = 1.f / (1.f + __expf(-(acc + bptr[0])));
}

// ---------------------------------------------------------------------------
// Scatter: head-mean of Pg + copy gate, atomically into out (pre-zeroed)
// ---------------------------------------------------------------------------
__global__ void scatter2_kernel(const int* __restrict__ src,
                                const int* __restrict__ onto,
                                const __hip_bfloat16* __restrict__ Pg,
                                const float* __restrict__ op,
                                const float* __restrict__ cp,
                                float* __restrict__ out) {
  long long i = (long long)blockIdx.x * blockDim.x + threadIdx.x;
  const long long nsrc = (long long)B * T * S;
  const long long nonto = (long long)B * T * O;
  if (i < nsrc) {
    int s = (int)(i & (S - 1));
    int bt = (int)(i >> 9);
    int b = bt >> 8;
    int t = bt & (T - 1);
    const unsigned short* pg = (const unsigned short*)Pg;
    float sum = 0.f;
#pragma unroll
    for (int h = 0; h < H; ++h)
      sum += b2f(pg[(((size_t)(b * H + h)) * T + t) * S + s]);
    float val = sum * (1.0f / (float)H) * cp[bt];
    atomicAdd(&out[(size_t)bt * V + src[b * S + s]], val);
  } else if (i < nsrc + nonto) {
    long long j = i - nsrc;
    int o = (int)(j % O);
    long long bt = j / O;
    float val = op[j] * (1.f - cp[bt]);
    atomicAdd(&out[bt * V + onto[o]], val);
  }
}

// ---------------------------------------------------------------------------
extern "C" void kernel_launch(void* const* d_in, const int* in_sizes, int n_in,
                              void* d_out, int out_size, void* d_ws, size_t ws_size,
                              hipStream_t stream) {
  const int* src_ids = (const int*)d_in[0];
  const float* enc = (const float*)d_in[1];
  const unsigned char* mask = (const unsigned char*)d_in[2];
  const float* dec = (const float*)d_in[3];
  const int* onto_ids = (const int*)d_in[4];
  const float* Wq = (const float*)d_in[5];
  const float* bq = (const float*)d_in[6];
  const float* Wk = (const float*)d_in[7];
  const float* bk = (const float*)d_in[8];
  const float* Wv = (const float*)d_in[9];
  const float* bv = (const float*)d_in[10];
  const float* Wo = (const float*)d_in[11];
  const float* bo = (const float*)d_in[12];
  const float* copy_w = (const float*)d_in[13];
  const float* copy_b = (const float*)d_in[14];
  const float* W1 = (const float*)d_in[15];
  const float* b1 = (const float*)d_in[16];
  const float* W2 = (const float*)d_in[17];
  const float* b2 = (const float*)d_in[18];

  const int MT = B * T;   // 2048
  const int MS = B * S;   // 4096

  // bf16 workspace (persistent region)
  __hip_bfloat16* wb = (__hip_bfloat16*)d_ws;
  __hip_bfloat16* qb16 = wb;    wb += (size_t)MT * D;
  __hip_bfloat16* kb16 = wb;    wb += (size_t)MS * D;
  __hip_bfloat16* vt = wb;      wb += (size_t)MS * D;        // [b][h][d][s]
  __hip_bfloat16* ctxb16 = wb;  wb += (size_t)MT * D;
  __hip_bfloat16* W2b = wb;     wb += (size_t)O * HID;
  __hip_bfloat16* Wob = wb;     wb += (size_t)D * D;
  __hip_bfloat16* WB = wb;      wb += (size_t)2 * D * D;     // [Wk; Wv]
  __hip_bfloat16* WA = wb;      wb += (size_t)(HID + D) * D; // [W1; Wq]
  // transient region aliased by Pg (decb/encb/hb16 all dead before attn3)
  __hip_bfloat16* Pg = wb;
  __hip_bfloat16* decb = wb;
  __hip_bfloat16* encb = decb + (size_t)MT * D;
  __hip_bfloat16* hb16 = encb + (size_t)MS * D;
  wb += (size_t)B * H * T * S;  // 12.58M elems >= 11.01M transient
  // fp32 workspace
  float* wf = (float*)wb;
  float* logits = wf;           wf += (size_t)MT * O;
  float* ontop = wf;            wf += (size_t)MT * O;
  float* ctxout = wf;           wf += (size_t)MT * D;
  float* cp = wf;               wf += (size_t)MT;

  float* out = (float*)d_out;

  // Zero output (nontemporal float4)
  {
    long long n4 = (long long)B * T * V / 4;
    zero_out_kernel<<<4096, 256, 0, stream>>>((f32x4*)out, n4);
  }

  // All fp32->bf16 conversions in one launch
  cvt_all_kernel<<<CH7 / 256, 256, 0, stream>>>(
      dec, enc, W1, Wq, Wk, Wv, W2, Wo,
      decb, encb, WA, WB, W2b, Wob);

  // enc @ [Wk;Wv]  -> kb16 + vt(transposed)
  gemm_mfma_kernel<128, 2><<<dim3((2 * D) / 128, MS / 128), 256, 0, stream>>>(
      encb, WB, bk, bv, nullptr, kb16, vt, MS, 2 * D, D);
  // dec @ [W1;Wq]  -> hb16(relu) + qb16
  gemm_mfma_kernel<128, 1><<<dim3((HID + D) / 128, MT / 128), 256, 0, stream>>>(
      decb, WA, b1, bq, nullptr, hb16, qb16, MT, HID + D, D);
  // FFN2
  gemm_mfma_kernel<64, 0><<<dim3(1, MT / 128), 256, 0, stream>>>(
      hb16, W2b, b2, nullptr, logits, nullptr, nullptr, MT, O, HID);
  softmax64_kernel<<<MT / 4, 256, 0, stream>>>(logits, ontop, MT);

  // Attention (Pg alias region dead from here on)
  attention3_kernel<<<B * H * (T / 32), 256, 0, stream>>>(
      qb16, kb16, vt, mask, ctxb16, Pg);

  // Output projection + copy head
  gemm_mfma_kernel<128, 0><<<dim3(D / 128, MT / 128), 256, 0, stream>>>(
      ctxb16, Wob, bo, nullptr, ctxout, nullptr, nullptr, MT, D, D);
  copy_head_kernel<<<MT / 4, 256, 0, stream>>>(ctxout, copy_w, copy_b, cp, MT);

  // Scatter
  long long total = (long long)B * T * (S + O);
  int nblk = (int)((total + 255) / 256);
  scatter2_kernel<<<nblk, 256, 0, stream>>>(src_ids, onto_ids, Pg, ontop, cp, out);
}

// Round 7
// 304.368 us; speedup vs baseline: 1.2434x; 1.1637x over previous
//
#include <hip/hip_runtime.h>
#include <hip/hip_bf16.h>
#include <math.h>

// Problem constants
constexpr int B = 8, S = 512, T = 256, D = 768, H = 12, HID = 3072;
constexpr int V = 50257, O = 64, HD = 64;

typedef short bf16x8 __attribute__((ext_vector_type(8)));
typedef float f32x4 __attribute__((ext_vector_type(4)));

__device__ __forceinline__ float b2f(unsigned short u) {
  union { float f; unsigned v; } x; x.v = ((unsigned)u) << 16; return x.f;
}
__device__ __forceinline__ unsigned short f2b(float f) {
  __hip_bfloat16 h = __float2bfloat16(f);
  return *(unsigned short*)&h;
}

__device__ __forceinline__ void async16(const void* g, void* l) {
  __builtin_amdgcn_global_load_lds(
      (const __attribute__((address_space(1))) void*)g,
      (__attribute__((address_space(3))) void*)l, 16, 0, 0);
}

// ---------------------------------------------------------------------------
// Fused fp32->bf16 conversion (7 regions, one launch). Chunks of 8 elems.
//   dec->decb | enc->encb | W1->WA[0] | Wq->WA[HID*D] | Wk->WB[0]
//   Wv->WB[D*D] | W2->W2b
// ---------------------------------------------------------------------------
constexpr int CH0 = B * T * D / 8;
constexpr int CH1 = CH0 + B * S * D / 8;
constexpr int CH2 = CH1 + HID * D / 8;
constexpr int CH3 = CH2 + D * D / 8;
constexpr int CH4 = CH3 + D * D / 8;
constexpr int CH5 = CH4 + D * D / 8;
constexpr int CH6 = CH5 + O * HID / 8;   // total chunks (divisible by 256)

__global__ void cvt_all_kernel(
    const float* __restrict__ dec, const float* __restrict__ enc,
    const float* __restrict__ W1, const float* __restrict__ Wq,
    const float* __restrict__ Wk, const float* __restrict__ Wv,
    const float* __restrict__ W2,
    __hip_bfloat16* __restrict__ decb, __hip_bfloat16* __restrict__ encb,
    __hip_bfloat16* __restrict__ WA, __hip_bfloat16* __restrict__ WB,
    __hip_bfloat16* __restrict__ W2b) {
  int i = blockIdx.x * blockDim.x + threadIdx.x;
  const float* src;
  __hip_bfloat16* dst;
  int j;
  if (i < CH0)      { src = dec; dst = decb;                 j = i; }
  else if (i < CH1) { src = enc; dst = encb;                 j = i - CH0; }
  else if (i < CH2) { src = W1;  dst = WA;                   j = i - CH1; }
  else if (i < CH3) { src = Wq;  dst = WA + (size_t)HID * D; j = i - CH2; }
  else if (i < CH4) { src = Wk;  dst = WB;                   j = i - CH3; }
  else if (i < CH5) { src = Wv;  dst = WB + (size_t)D * D;   j = i - CH4; }
  else if (i < CH6) { src = W2;  dst = W2b;                  j = i - CH5; }
  else return;
  size_t e = (size_t)j * 8;
  float4 v0 = *(const float4*)&src[e];
  float4 v1 = *(const float4*)&src[e + 4];
  ushort4 o0, o1;
  o0.x = f2b(v0.x); o0.y = f2b(v0.y); o0.z = f2b(v0.z); o0.w = f2b(v0.w);
  o1.x = f2b(v1.x); o1.y = f2b(v1.y); o1.z = f2b(v1.z); o1.w = f2b(v1.w);
  *(ushort4*)&dst[e] = o0;
  *(ushort4*)&dst[e + 4] = o1;
}

// ---------------------------------------------------------------------------
// w_eff[i] = sum_o Wo[o,i]*copy_w[o];  w_eff[D] = sum_o bo[o]*copy_w[o]+cb
// (replaces the whole output-projection GEMM: it only feeds the copy gate)
// ---------------------------------------------------------------------------
__global__ void weff_kernel(const float* __restrict__ Wo,
                            const float* __restrict__ bo,
                            const float* __restrict__ cw,
                            const float* __restrict__ cb,
                            float* __restrict__ weff) {
  int i = blockIdx.x * blockDim.x + threadIdx.x;
  if (i < D) {
    float acc = 0.f;
    for (int o = 0; o < D; ++o) acc += Wo[(size_t)o * D + i] * cw[o];
    weff[i] = acc;
  } else if (i == D) {
    float acc = cb[0];
    for (int o = 0; o < D; ++o) acc += bo[o] * cw[o];
    weff[D] = acc;
  }
}

// ---------------------------------------------------------------------------
// Shared GEMM body. C = A[M,K] @ W[N,K]^T, BM=128, BN in {64,128}, BK=32.
// MODE 1: c<HID -> out0=relu+bias0 (bf16 [r*HID+c]); else out1=+bias1
//         (bf16 [r*D + c-HID])                        (FFN1 + Q)
// MODE 2: c<D -> out0=+bias0 (bf16 [r*D+c]); else out1 vt-transposed +bias1
//                                                     (K + V)
// MODE 3: Cf[r*N+c] = raw acc (fp32, no bias)         (split-K partial)
// ---------------------------------------------------------------------------
template <int BN, int MODE>
__device__ __forceinline__ void gemm_body(
    const __hip_bfloat16* __restrict__ A, const __hip_bfloat16* __restrict__ W,
    const float* __restrict__ bias0, const float* __restrict__ bias1,
    float* __restrict__ Cf, __hip_bfloat16* __restrict__ out0,
    __hip_bfloat16* __restrict__ out1, int M, int N, int K,
    int bx, int by, int kbeg, int kend,
    __hip_bfloat16* Als, __hip_bfloat16* Bls) {
  constexpr int BK = 32;
  constexpr int WTN = BN / 2;
  constexpr int NFRAG = WTN / 16;
  const int tid = threadIdx.x;
  const int lane = tid & 63, wid = tid >> 6;
  const int wm = wid >> 1, wn = wid & 1;
  const int row0 = by * 128, col0 = bx * BN;
  const int lr = lane & 15;
  const int ko = (lane >> 4) * 8;

  f32x4 acc[4][NFRAG] = {};

  for (int k0 = kbeg; k0 < kend; k0 += BK) {
#pragma unroll
    for (int c = 0; c < 2; ++c) {
      int j = tid + c * 256;
      int r = j >> 2, col = (j & 3) * 8;
      async16(&A[(size_t)(row0 + r) * K + k0 + col], (void*)&Als[j * 8]);
    }
#pragma unroll
    for (int c = 0; c < BN / 64; ++c) {
      int j = tid + c * 256;
      int r = j >> 2, col = (j & 3) * 8;
      async16(&W[(size_t)(col0 + r) * K + k0 + col], (void*)&Bls[j * 8]);
    }
    __syncthreads();

    bf16x8 af[4], bfr[NFRAG];
#pragma unroll
    for (int mi = 0; mi < 4; ++mi)
      af[mi] = *(const bf16x8*)&Als[(wm * 64 + mi * 16 + lr) * BK + ko];
#pragma unroll
    for (int ni = 0; ni < NFRAG; ++ni)
      bfr[ni] = *(const bf16x8*)&Bls[(wn * WTN + ni * 16 + lr) * BK + ko];
#pragma unroll
    for (int mi = 0; mi < 4; ++mi)
#pragma unroll
      for (int ni = 0; ni < NFRAG; ++ni)
        acc[mi][ni] = __builtin_amdgcn_mfma_f32_16x16x32_bf16(
            af[mi], bfr[ni], acc[mi][ni], 0, 0, 0);
    __syncthreads();
  }

#pragma unroll
  for (int mi = 0; mi < 4; ++mi) {
    int rbase = row0 + wm * 64 + mi * 16 + (lane >> 4) * 4;
#pragma unroll
    for (int ni = 0; ni < NFRAG; ++ni) {
      int c = col0 + wn * WTN + ni * 16 + lr;
#pragma unroll
      for (int r = 0; r < 4; ++r) {
        int rr = rbase + r;
        float a = acc[mi][ni][r];
        if constexpr (MODE == 1) {
          if (c < HID) {
            out0[(size_t)rr * HID + c] = __float2bfloat16(fmaxf(a + bias0[c], 0.f));
          } else {
            out1[(size_t)rr * D + (c - HID)] = __float2bfloat16(a + bias1[c - HID]);
          }
        } else if constexpr (MODE == 2) {
          if (c < D) {
            out0[(size_t)rr * D + c] = __float2bfloat16(a + bias0[c]);
          } else {
            int d = c - D;
            size_t idx = (((size_t)(rr >> 9) * D + d) << 9) | (size_t)(rr & 511);
            out1[idx] = __float2bfloat16(a + bias1[d]);
          }
        } else {
          Cf[(size_t)rr * N + c] = a;
        }
      }
    }
  }
}

// Merged KV + FFN1Q launch: blocks [0,384) -> K/V proj, [384,864) -> FFN1+Q
constexpr int KV_BX = (2 * D) / 128;                 // 12
constexpr int KV_BLOCKS = KV_BX * (B * S / 128);     // 384
constexpr int FQ_BX = (HID + D) / 128;               // 30
constexpr int FQ_BLOCKS = FQ_BX * (B * T / 128);     // 480

__global__ __launch_bounds__(256) void gemm_mega_kernel(
    const __hip_bfloat16* __restrict__ encb, const __hip_bfloat16* __restrict__ WB,
    const float* __restrict__ bk, const float* __restrict__ bv,
    __hip_bfloat16* __restrict__ kb16, __hip_bfloat16* __restrict__ vt,
    const __hip_bfloat16* __restrict__ decb, const __hip_bfloat16* __restrict__ WA,
    const float* __restrict__ b1, const float* __restrict__ bq,
    __hip_bfloat16* __restrict__ hb16, __hip_bfloat16* __restrict__ qb16) {
  __shared__ __hip_bfloat16 Als[128 * 32];
  __shared__ __hip_bfloat16 Bls[128 * 32];
  int bid = blockIdx.x;
  if (bid < KV_BLOCKS) {
    gemm_body<128, 2>(encb, WB, bk, bv, nullptr, kb16, vt,
                      B * S, 2 * D, D, bid % KV_BX, bid / KV_BX, 0, D, Als, Bls);
  } else {
    int r = bid - KV_BLOCKS;
    gemm_body<128, 1>(decb, WA, b1, bq, nullptr, hb16, qb16,
                      B * T, HID + D, D, r % FQ_BX, r / FQ_BX, 0, D, Als, Bls);
  }
}

// FFN2 split-K: 16 splits x 16 M-tiles, K-chunk 192 -> fp32 partials
constexpr int NSPLIT = 16;
constexpr int KCH = HID / NSPLIT;  // 192

__global__ __launch_bounds__(256) void gemm_ffn2_kernel(
    const __hip_bfloat16* __restrict__ hb16, const __hip_bfloat16* __restrict__ W2b,
    float* __restrict__ part) {
  __shared__ __hip_bfloat16 Als[128 * 32];
  __shared__ __hip_bfloat16 Bls[64 * 32];
  int sp = blockIdx.x, mt = blockIdx.y;
  gemm_body<64, 3>(hb16, W2b, nullptr, nullptr,
                   part + (size_t)sp * (B * T) * 64, nullptr, nullptr,
                   B * T, 64, HID, 0, mt, sp * KCH, (sp + 1) * KCH, Als, Bls);
}

// ---------------------------------------------------------------------------
// Reduce 16 split-K partials + bias + softmax over O=64 (one wave per row)
// ---------------------------------------------------------------------------
__global__ void softmax_reduce_kernel(const float* __restrict__ part,
                                      const float* __restrict__ b2v,
                                      float* __restrict__ probs, int rows) {
  int row = blockIdx.x * (blockDim.x >> 6) + (threadIdx.x >> 6);
  int lane = threadIdx.x & 63;
  if (row >= rows) return;
  float x = b2v[lane];
#pragma unroll
  for (int sp = 0; sp < NSPLIT; ++sp)
    x += part[((size_t)sp * rows + row) * 64 + lane];
  float m = x;
#pragma unroll
  for (int o = 32; o > 0; o >>= 1) m = fmaxf(m, __shfl_xor(m, o));
  float e = __expf(x - m);
  float ss = e;
#pragma unroll
  for (int o = 32; o > 0; o >>= 1) ss += __shfl_xor(ss, o);
  probs[(size_t)row * 64 + lane] = e / ss;
}

// ---------------------------------------------------------------------------
// Attention v3 (MFMA): one block (256 thr = 4 waves) per (b, h, 32-t tile).
// ---------------------------------------------------------------------------
__global__ __launch_bounds__(256) void attention3_kernel(
    const __hip_bfloat16* __restrict__ q, const __hip_bfloat16* __restrict__ k,
    const __hip_bfloat16* __restrict__ vt, const unsigned char* __restrict__ mask,
    __hip_bfloat16* __restrict__ ctx, __hip_bfloat16* __restrict__ Pg) {
  constexpr int TB = 32;
  constexpr int SCP = 520;
  __shared__ __hip_bfloat16 Qls[TB * 64];
  __shared__ __hip_bfloat16 KVls[128 * 64];
  __shared__ __hip_bfloat16 sc[TB * SCP];
  const int tid = threadIdx.x;
  const int lane = tid & 63, w = tid >> 6;
  const int lr = lane & 15, lg = lane >> 4;
  const int bid = blockIdx.x;
  const int tile = bid & 7;
  const int h = (bid >> 3) % H;
  const int b = bid / (8 * H);
  const int t0 = tile * TB;

  {
    int r = tid >> 3, slot = tid & 7;
    int g = slot ^ (r & 7);
    async16(&q[((size_t)(b * T + t0 + r)) * D + h * 64 + g * 8],
            (void*)&Qls[tid * 8]);
  }

  for (int ch = 0; ch < 4; ++ch) {
    const int s0 = ch * 128;
#pragma unroll
    for (int it = 0; it < 4; ++it) {
      int c = tid + it * 256;
      int r = c >> 3, slot = c & 7;
      int g = slot ^ (r & 7);
      async16(&k[((size_t)(b * S + s0 + r)) * D + h * 64 + g * 8],
              (void*)&KVls[c * 8]);
    }
    __syncthreads();
    f32x4 acc[2][2] = {};
#pragma unroll
    for (int ks = 0; ks < 2; ++ks) {
      bf16x8 af[2], bfr[2];
#pragma unroll
      for (int mi = 0; mi < 2; ++mi) {
        int row = mi * 16 + lr;
        int slot = (4 * ks + lg) ^ (row & 7);
        af[mi] = *(const bf16x8*)&Qls[row * 64 + slot * 8];
      }
#pragma unroll
      for (int ni = 0; ni < 2; ++ni) {
        int row = w * 32 + ni * 16 + lr;
        int slot = (4 * ks + lg) ^ (row & 7);
        bfr[ni] = *(const bf16x8*)&KVls[row * 64 + slot * 8];
      }
#pragma unroll
      for (int mi = 0; mi < 2; ++mi)
#pragma unroll
        for (int ni = 0; ni < 2; ++ni)
          acc[mi][ni] = __builtin_amdgcn_mfma_f32_16x16x32_bf16(
              af[mi], bfr[ni], acc[mi][ni], 0, 0, 0);
    }
#pragma unroll
    for (int ni = 0; ni < 2; ++ni) {
      int s_local = w * 32 + ni * 16 + lr;
      bool msk = mask[b * S + s0 + s_local];
#pragma unroll
      for (int mi = 0; mi < 2; ++mi) {
        int trow = mi * 16 + lg * 4;
#pragma unroll
        for (int rg = 0; rg < 4; ++rg) {
          float val = msk ? -INFINITY : acc[mi][ni][rg] * 0.125f;
          sc[(trow + rg) * SCP + s0 + s_local] = __float2bfloat16(val);
        }
      }
    }
    __syncthreads();
  }

  unsigned short* scu = (unsigned short*)sc;
  unsigned short* pgu = (unsigned short*)Pg;
#pragma unroll
  for (int i = 0; i < 8; ++i) {
    int r = w * 8 + i;
    float x[8];
    float m = -INFINITY;
#pragma unroll
    for (int j = 0; j < 8; ++j) {
      x[j] = b2f(scu[r * SCP + j * 64 + lane]);
      m = fmaxf(m, x[j]);
    }
#pragma unroll
    for (int o = 32; o > 0; o >>= 1) m = fmaxf(m, __shfl_xor(m, o));
    float ssum = 0.f;
#pragma unroll
    for (int j = 0; j < 8; ++j) { x[j] = __expf(x[j] - m); ssum += x[j]; }
#pragma unroll
    for (int o = 32; o > 0; o >>= 1) ssum += __shfl_xor(ssum, o);
    float inv = 1.f / ssum;
#pragma unroll
    for (int j = 0; j < 8; ++j) {
      unsigned short pb = f2b(x[j] * inv);
      scu[r * SCP + j * 64 + lane] = pb;
      pgu[(((size_t)(b * H + h)) * T + t0 + r) * S + j * 64 + lane] = pb;
    }
  }
  __syncthreads();

  f32x4 accp[2] = {};
  for (int ch = 0; ch < 4; ++ch) {
    const int s0 = ch * 128;
#pragma unroll
    for (int it = 0; it < 4; ++it) {
      int c = tid + it * 256;
      int d = c >> 4, slot = c & 15;
      int g = slot ^ (d & 7);
      async16(&vt[(((size_t)(b * H + h)) * 64 + d) * S + s0 + g * 8],
              (void*)&KVls[c * 8]);
    }
    __syncthreads();
#pragma unroll
    for (int ks = 0; ks < 4; ++ks) {
      bf16x8 bfr;
      {
        int brow = w * 16 + lr;
        int slot = (4 * ks + lg) ^ (brow & 7);
        bfr = *(const bf16x8*)&KVls[brow * 128 + slot * 8];
      }
#pragma unroll
      for (int mi = 0; mi < 2; ++mi) {
        int prow = mi * 16 + lr;
        bf16x8 af = *(const bf16x8*)&sc[prow * SCP + s0 + ks * 32 + lg * 8];
        accp[mi] = __builtin_amdgcn_mfma_f32_16x16x32_bf16(af, bfr, accp[mi], 0, 0, 0);
      }
    }
    __syncthreads();
  }
#pragma unroll
  for (int mi = 0; mi < 2; ++mi) {
    int trow = mi * 16 + lg * 4;
#pragma unroll
    for (int rg = 0; rg < 4; ++rg) {
      ctx[((size_t)(b * T + t0 + trow + rg)) * D + h * 64 + w * 16 + lr] =
          __float2bfloat16(accp[mi][rg]);
    }
  }
}

// ---------------------------------------------------------------------------
// Copy head on bf16 ctx with precomputed w_eff (one wave per row)
// ---------------------------------------------------------------------------
__global__ void copy_head2_kernel(const __hip_bfloat16* __restrict__ ctx,
                                  const float* __restrict__ weff,
                                  float* __restrict__ cpout, int rows) {
  int row = blockIdx.x * (blockDim.x >> 6) + (threadIdx.x >> 6);
  int lane = threadIdx.x & 63;
  if (row >= rows) return;
  const unsigned short* cu = (const unsigned short*)ctx;
  float acc = 0.f;
#pragma unroll
  for (int j = 0; j < D / 64; ++j) {
    int d = j * 64 + lane;
    acc += b2f(cu[(size_t)row * D + d]) * weff[d];
  }
#pragma unroll
  for (int o = 32; o > 0; o >>= 1) acc += __shfl_xor(acc, o);
  if (lane == 0) cpout[row] = 1.f / (1.f + __expf(-(acc + weff[D])));
}

// ---------------------------------------------------------------------------
// Fused zero + scatter: one block per (b,t) row. Zeroes the V-row, then
// adds this row's source & ontology contributions (row-exclusive: no
// cross-block races; __syncthreads drains the zero-stores first).
// ---------------------------------------------------------------------------
__global__ __launch_bounds__(256) void scatter_fused_kernel(
    const int* __restrict__ src, const int* __restrict__ onto,
    const __hip_bfloat16* __restrict__ Pg, const float* __restrict__ op,
    const float* __restrict__ cp, float* __restrict__ out) {
  const int bt = blockIdx.x;           // B*T
  const int b = bt >> 8, t = bt & (T - 1);
  const int tid = threadIdx.x;
  float* row = out + (size_t)bt * V;

  // phase A: zero the row (handle 16B alignment of the row start)
  uintptr_t addr = (uintptr_t)row;
  int head = (int)(((16 - (addr & 15)) & 15) >> 2);
  if (tid < head) row[tid] = 0.f;
  int n4 = (V - head) >> 2;
  f32x4* row4 = (f32x4*)(row + head);
  const f32x4 z = {0.f, 0.f, 0.f, 0.f};
  for (int i = tid; i < n4; i += 256) row4[i] = z;
  int tail0 = head + (n4 << 2);
  if (tid < V - tail0) row[tail0 + tid] = 0.f;
  __syncthreads();

  // phase B: source scatter (512 ids)
  const float cpv = cp[bt];
  const unsigned short* pg = (const unsigned short*)Pg;
  for (int s = tid; s < S; s += 256) {
    float sum = 0.f;
#pragma unroll
    for (int h = 0; h < H; ++h)
      sum += b2f(pg[(((size_t)(b * H + h)) * T + t) * S + s]);
    atomicAdd(&row[src[b * S + s]], sum * (1.0f / (float)H) * cpv);
  }
  // phase C: ontology (64 ids)
  if (tid < O) {
    atomicAdd(&row[onto[tid]], op[(size_t)bt * O + tid] * (1.f - cpv));
  }
}

// ---------------------------------------------------------------------------
extern "C" void kernel_launch(void* const* d_in, const int* in_sizes, int n_in,
                              void* d_out, int out_size, void* d_ws, size_t ws_size,
                              hipStream_t stream) {
  const int* src_ids = (const int*)d_in[0];
  const float* enc = (const float*)d_in[1];
  const unsigned char* mask = (const unsigned char*)d_in[2];
  const float* dec = (const float*)d_in[3];
  const int* onto_ids = (const int*)d_in[4];
  const float* Wq = (const float*)d_in[5];
  const float* bq = (const float*)d_in[6];
  const float* Wk = (const float*)d_in[7];
  const float* bk = (const float*)d_in[8];
  const float* Wv = (const float*)d_in[9];
  const float* bv = (const float*)d_in[10];
  const float* Wo = (const float*)d_in[11];
  const float* bo = (const float*)d_in[12];
  const float* copy_w = (const float*)d_in[13];
  const float* copy_b = (const float*)d_in[14];
  const float* W1 = (const float*)d_in[15];
  const float* b1 = (const float*)d_in[16];
  const float* W2 = (const float*)d_in[17];
  const float* b2 = (const float*)d_in[18];

  const int MT = B * T;   // 2048
  const int MS = B * S;   // 4096

  // bf16 workspace (persistent)
  __hip_bfloat16* wb = (__hip_bfloat16*)d_ws;
  __hip_bfloat16* qb16 = wb;    wb += (size_t)MT * D;
  __hip_bfloat16* kb16 = wb;    wb += (size_t)MS * D;
  __hip_bfloat16* vt = wb;      wb += (size_t)MS * D;        // [b][h][d][s]
  __hip_bfloat16* ctxb16 = wb;  wb += (size_t)MT * D;
  __hip_bfloat16* W2b = wb;     wb += (size_t)O * HID;
  __hip_bfloat16* WB = wb;      wb += (size_t)2 * D * D;     // [Wk; Wv]
  __hip_bfloat16* WA = wb;      wb += (size_t)(HID + D) * D; // [W1; Wq]
  // transient region aliased by Pg (decb/encb/hb16 dead before attention3)
  __hip_bfloat16* Pg = wb;
  __hip_bfloat16* decb = wb;
  __hip_bfloat16* encb = decb + (size_t)MT * D;
  __hip_bfloat16* hb16 = encb + (size_t)MS * D;
  wb += (size_t)B * H * T * S;  // 12.58M elems >= 11.01M transient
  // fp32 workspace
  float* wf = (float*)wb;
  float* part = wf;             wf += (size_t)NSPLIT * MT * O;  // split-K partials
  float* ontop = wf;            wf += (size_t)MT * O;
  float* cp = wf;               wf += (size_t)MT;
  float* weff = wf;             wf += (size_t)(D + 1);

  float* out = (float*)d_out;

  // w_eff (tiny, independent)
  weff_kernel<<<4, 256, 0, stream>>>(Wo, bo, copy_w, copy_b, weff);

  // all fp32->bf16 conversions
  cvt_all_kernel<<<CH6 / 256, 256, 0, stream>>>(
      dec, enc, W1, Wq, Wk, Wv, W2, decb, encb, WA, WB, W2b);

  // merged K/V + FFN1/Q projections (864 blocks)
  gemm_mega_kernel<<<KV_BLOCKS + FQ_BLOCKS, 256, 0, stream>>>(
      encb, WB, bk, bv, kb16, vt, decb, WA, b1, bq, hb16, qb16);

  // FFN2 split-K (256 blocks) + fused reduce/bias/softmax
  gemm_ffn2_kernel<<<dim3(NSPLIT, MT / 128), 256, 0, stream>>>(hb16, W2b, part);
  softmax_reduce_kernel<<<MT / 4, 256, 0, stream>>>(part, b2, ontop, MT);

  // attention (Pg alias region dead from here on)
  attention3_kernel<<<B * H * (T / 32), 256, 0, stream>>>(
      qb16, kb16, vt, mask, ctxb16, Pg);

  // copy gate directly from ctx via w_eff
  copy_head2_kernel<<<MT / 4, 256, 0, stream>>>(ctxb16, weff, cp, MT);

  // fused zero + scatter (one block per output row)
  scatter_fused_kernel<<<MT, 256, 0, stream>>>(
      src_ids, onto_ids, Pg, ontop, cp, out);
}

// Round 8
// 281.764 us; speedup vs baseline: 1.3431x; 1.0802x over previous
//
#include <hip/hip_runtime.h>
#include <hip/hip_bf16.h>
#include <math.h>

// Problem constants
constexpr int B = 8, S = 512, T = 256, D = 768, H = 12, HID = 3072;
constexpr int V = 50257, O = 64, HD = 64;

typedef short bf16x8 __attribute__((ext_vector_type(8)));
typedef float f32x4 __attribute__((ext_vector_type(4)));

__device__ __forceinline__ float b2f(unsigned short u) {
  union { float f; unsigned v; } x; x.v = ((unsigned)u) << 16; return x.f;
}
__device__ __forceinline__ unsigned short f2b(float f) {
  __hip_bfloat16 h = __float2bfloat16(f);
  return *(unsigned short*)&h;
}

__device__ __forceinline__ void async16(const void* g, void* l) {
  __builtin_amdgcn_global_load_lds(
      (const __attribute__((address_space(1))) void*)g,
      (__attribute__((address_space(3))) void*)l, 16, 0, 0);
}

// ---------------------------------------------------------------------------
// Fused fp32->bf16 conversion (7 regions) + w_eff computation (4 extra blocks)
//   dec->decb | enc->encb | W1->WA[0] | Wq->WA[HID*D] | Wk->WB[0]
//   Wv->WB[D*D] | W2->W2b | weff[i]=sum_o Wo[o,i]*cw[o], weff[D]=bo.cw+cb
// ---------------------------------------------------------------------------
constexpr int CH0 = B * T * D / 8;
constexpr int CH1 = CH0 + B * S * D / 8;
constexpr int CH2 = CH1 + HID * D / 8;
constexpr int CH3 = CH2 + D * D / 8;
constexpr int CH4 = CH3 + D * D / 8;
constexpr int CH5 = CH4 + D * D / 8;
constexpr int CH6 = CH5 + O * HID / 8;   // total cvt chunks (divisible by 256)

__global__ void cvt_weff_kernel(
    const float* __restrict__ dec, const float* __restrict__ enc,
    const float* __restrict__ W1, const float* __restrict__ Wq,
    const float* __restrict__ Wk, const float* __restrict__ Wv,
    const float* __restrict__ W2, const float* __restrict__ Wo,
    const float* __restrict__ bo, const float* __restrict__ cw,
    const float* __restrict__ cb,
    __hip_bfloat16* __restrict__ decb, __hip_bfloat16* __restrict__ encb,
    __hip_bfloat16* __restrict__ WA, __hip_bfloat16* __restrict__ WB,
    __hip_bfloat16* __restrict__ W2b, float* __restrict__ weff) {
  int i = blockIdx.x * blockDim.x + threadIdx.x;
  if (i >= CH6) {
    // w_eff tail work
    int j = i - CH6;
    if (j < D) {
      float acc = 0.f;
      for (int o = 0; o < D; ++o) acc += Wo[(size_t)o * D + j] * cw[o];
      weff[j] = acc;
    } else if (j == D) {
      float acc = cb[0];
      for (int o = 0; o < D; ++o) acc += bo[o] * cw[o];
      weff[D] = acc;
    }
    return;
  }
  const float* src;
  __hip_bfloat16* dst;
  int j;
  if (i < CH0)      { src = dec; dst = decb;                 j = i; }
  else if (i < CH1) { src = enc; dst = encb;                 j = i - CH0; }
  else if (i < CH2) { src = W1;  dst = WA;                   j = i - CH1; }
  else if (i < CH3) { src = Wq;  dst = WA + (size_t)HID * D; j = i - CH2; }
  else if (i < CH4) { src = Wk;  dst = WB;                   j = i - CH3; }
  else if (i < CH5) { src = Wv;  dst = WB + (size_t)D * D;   j = i - CH4; }
  else              { src = W2;  dst = W2b;                  j = i - CH5; }
  size_t e = (size_t)j * 8;
  float4 v0 = *(const float4*)&src[e];
  float4 v1 = *(const float4*)&src[e + 4];
  ushort4 o0, o1;
  o0.x = f2b(v0.x); o0.y = f2b(v0.y); o0.z = f2b(v0.z); o0.w = f2b(v0.w);
  o1.x = f2b(v1.x); o1.y = f2b(v1.y); o1.z = f2b(v1.z); o1.w = f2b(v1.w);
  *(ushort4*)&dst[e] = o0;
  *(ushort4*)&dst[e + 4] = o1;
}

// ---------------------------------------------------------------------------
// Shared GEMM body (BM=128, BN in {64,128}, BK=32, 256 thr).
// MODE 1: FFN1(relu)+Q split epilogue. MODE 2: K + V(transposed) epilogue.
// MODE 3: raw fp32 partial (split-K).
// ---------------------------------------------------------------------------
template <int BN, int MODE>
__device__ __forceinline__ void gemm_body(
    const __hip_bfloat16* __restrict__ A, const __hip_bfloat16* __restrict__ W,
    const float* __restrict__ bias0, const float* __restrict__ bias1,
    float* __restrict__ Cf, __hip_bfloat16* __restrict__ out0,
    __hip_bfloat16* __restrict__ out1, int M, int N, int K,
    int bx, int by, int kbeg, int kend,
    __hip_bfloat16* Als, __hip_bfloat16* Bls) {
  constexpr int BK = 32;
  constexpr int WTN = BN / 2;
  constexpr int NFRAG = WTN / 16;
  const int tid = threadIdx.x;
  const int lane = tid & 63, wid = tid >> 6;
  const int wm = wid >> 1, wn = wid & 1;
  const int row0 = by * 128, col0 = bx * BN;
  const int lr = lane & 15;
  const int ko = (lane >> 4) * 8;

  f32x4 acc[4][NFRAG] = {};

  for (int k0 = kbeg; k0 < kend; k0 += BK) {
#pragma unroll
    for (int c = 0; c < 2; ++c) {
      int j = tid + c * 256;
      int r = j >> 2, col = (j & 3) * 8;
      async16(&A[(size_t)(row0 + r) * K + k0 + col], (void*)&Als[j * 8]);
    }
#pragma unroll
    for (int c = 0; c < BN / 64; ++c) {
      int j = tid + c * 256;
      int r = j >> 2, col = (j & 3) * 8;
      async16(&W[(size_t)(col0 + r) * K + k0 + col], (void*)&Bls[j * 8]);
    }
    __syncthreads();

    bf16x8 af[4], bfr[NFRAG];
#pragma unroll
    for (int mi = 0; mi < 4; ++mi)
      af[mi] = *(const bf16x8*)&Als[(wm * 64 + mi * 16 + lr) * BK + ko];
#pragma unroll
    for (int ni = 0; ni < NFRAG; ++ni)
      bfr[ni] = *(const bf16x8*)&Bls[(wn * WTN + ni * 16 + lr) * BK + ko];
#pragma unroll
    for (int mi = 0; mi < 4; ++mi)
#pragma unroll
      for (int ni = 0; ni < NFRAG; ++ni)
        acc[mi][ni] = __builtin_amdgcn_mfma_f32_16x16x32_bf16(
            af[mi], bfr[ni], acc[mi][ni], 0, 0, 0);
    __syncthreads();
  }

#pragma unroll
  for (int mi = 0; mi < 4; ++mi) {
    int rbase = row0 + wm * 64 + mi * 16 + (lane >> 4) * 4;
#pragma unroll
    for (int ni = 0; ni < NFRAG; ++ni) {
      int c = col0 + wn * WTN + ni * 16 + lr;
#pragma unroll
      for (int r = 0; r < 4; ++r) {
        int rr = rbase + r;
        float a = acc[mi][ni][r];
        if constexpr (MODE == 1) {
          if (c < HID) {
            out0[(size_t)rr * HID + c] = __float2bfloat16(fmaxf(a + bias0[c], 0.f));
          } else {
            out1[(size_t)rr * D + (c - HID)] = __float2bfloat16(a + bias1[c - HID]);
          }
        } else if constexpr (MODE == 2) {
          if (c < D) {
            out0[(size_t)rr * D + c] = __float2bfloat16(a + bias0[c]);
          } else {
            int d = c - D;
            size_t idx = (((size_t)(rr >> 9) * D + d) << 9) | (size_t)(rr & 511);
            out1[idx] = __float2bfloat16(a + bias1[d]);
          }
        } else {
          Cf[(size_t)rr * N + c] = a;
        }
      }
    }
  }
}

// Mega launch: [0,384) K/V proj | [384,864) FFN1+Q | [864,2048) zero out
constexpr int KV_BX = (2 * D) / 128;                 // 12
constexpr int KV_BLOCKS = KV_BX * (B * S / 128);     // 384
constexpr int FQ_BX = (HID + D) / 128;               // 30
constexpr int FQ_BLOCKS = FQ_BX * (B * T / 128);     // 480
constexpr int GEMM_BLOCKS = KV_BLOCKS + FQ_BLOCKS;   // 864
constexpr int ZERO_BLOCKS = 1184;
constexpr long long OUT_N4 = (long long)B * T * V / 4;

__global__ __launch_bounds__(256) void gemm_mega_kernel(
    const __hip_bfloat16* __restrict__ encb, const __hip_bfloat16* __restrict__ WB,
    const float* __restrict__ bk, const float* __restrict__ bv,
    __hip_bfloat16* __restrict__ kb16, __hip_bfloat16* __restrict__ vt,
    const __hip_bfloat16* __restrict__ decb, const __hip_bfloat16* __restrict__ WA,
    const float* __restrict__ b1, const float* __restrict__ bq,
    __hip_bfloat16* __restrict__ hb16, __hip_bfloat16* __restrict__ qb16,
    float* __restrict__ out) {
  __shared__ __hip_bfloat16 Als[128 * 32];
  __shared__ __hip_bfloat16 Bls[128 * 32];
  int bid = blockIdx.x;
  if (bid < KV_BLOCKS) {
    gemm_body<128, 2>(encb, WB, bk, bv, nullptr, kb16, vt,
                      B * S, 2 * D, D, bid % KV_BX, bid / KV_BX, 0, D, Als, Bls);
  } else if (bid < GEMM_BLOCKS) {
    int r = bid - KV_BLOCKS;
    gemm_body<128, 1>(decb, WA, b1, bq, nullptr, hb16, qb16,
                      B * T, HID + D, D, r % FQ_BX, r / FQ_BX, 0, D, Als, Bls);
  } else {
    // zero the output buffer (overlaps with compute-bound GEMM blocks)
    long long zb = bid - GEMM_BLOCKS;
    f32x4* o4 = (f32x4*)out;
    const f32x4 z = {0.f, 0.f, 0.f, 0.f};
    for (long long i = zb * 256 + threadIdx.x; i < OUT_N4;
         i += (long long)ZERO_BLOCKS * 256)
      __builtin_nontemporal_store(z, &o4[i]);
  }
}

// FFN2 split-K: 16 splits x 16 M-tiles, K-chunk 192 -> fp32 partials
constexpr int NSPLIT = 16;
constexpr int KCH = HID / NSPLIT;  // 192

__global__ __launch_bounds__(256) void gemm_ffn2_kernel(
    const __hip_bfloat16* __restrict__ hb16, const __hip_bfloat16* __restrict__ W2b,
    float* __restrict__ part) {
  __shared__ __hip_bfloat16 Als[128 * 32];
  __shared__ __hip_bfloat16 Bls[64 * 32];
  int sp = blockIdx.x, mt = blockIdx.y;
  gemm_body<64, 3>(hb16, W2b, nullptr, nullptr,
                   part + (size_t)sp * (B * T) * 64, nullptr, nullptr,
                   B * T, 64, HID, 0, mt, sp * KCH, (sp + 1) * KCH, Als, Bls);
}

// ---------------------------------------------------------------------------
// Attention v3 (MFMA): one block (256 thr = 4 waves) per (b, h, 32-t tile).
// ---------------------------------------------------------------------------
__global__ __launch_bounds__(256) void attention3_kernel(
    const __hip_bfloat16* __restrict__ q, const __hip_bfloat16* __restrict__ k,
    const __hip_bfloat16* __restrict__ vt, const unsigned char* __restrict__ mask,
    __hip_bfloat16* __restrict__ ctx, __hip_bfloat16* __restrict__ Pg) {
  constexpr int TB = 32;
  constexpr int SCP = 520;
  __shared__ __hip_bfloat16 Qls[TB * 64];
  __shared__ __hip_bfloat16 KVls[128 * 64];
  __shared__ __hip_bfloat16 sc[TB * SCP];
  const int tid = threadIdx.x;
  const int lane = tid & 63, w = tid >> 6;
  const int lr = lane & 15, lg = lane >> 4;
  const int bid = blockIdx.x;
  const int tile = bid & 7;
  const int h = (bid >> 3) % H;
  const int b = bid / (8 * H);
  const int t0 = tile * TB;

  {
    int r = tid >> 3, slot = tid & 7;
    int g = slot ^ (r & 7);
    async16(&q[((size_t)(b * T + t0 + r)) * D + h * 64 + g * 8],
            (void*)&Qls[tid * 8]);
  }

  for (int ch = 0; ch < 4; ++ch) {
    const int s0 = ch * 128;
#pragma unroll
    for (int it = 0; it < 4; ++it) {
      int c = tid + it * 256;
      int r = c >> 3, slot = c & 7;
      int g = slot ^ (r & 7);
      async16(&k[((size_t)(b * S + s0 + r)) * D + h * 64 + g * 8],
              (void*)&KVls[c * 8]);
    }
    __syncthreads();
    f32x4 acc[2][2] = {};
#pragma unroll
    for (int ks = 0; ks < 2; ++ks) {
      bf16x8 af[2], bfr[2];
#pragma unroll
      for (int mi = 0; mi < 2; ++mi) {
        int row = mi * 16 + lr;
        int slot = (4 * ks + lg) ^ (row & 7);
        af[mi] = *(const bf16x8*)&Qls[row * 64 + slot * 8];
      }
#pragma unroll
      for (int ni = 0; ni < 2; ++ni) {
        int row = w * 32 + ni * 16 + lr;
        int slot = (4 * ks + lg) ^ (row & 7);
        bfr[ni] = *(const bf16x8*)&KVls[row * 64 + slot * 8];
      }
#pragma unroll
      for (int mi = 0; mi < 2; ++mi)
#pragma unroll
        for (int ni = 0; ni < 2; ++ni)
          acc[mi][ni] = __builtin_amdgcn_mfma_f32_16x16x32_bf16(
              af[mi], bfr[ni], acc[mi][ni], 0, 0, 0);
    }
#pragma unroll
    for (int ni = 0; ni < 2; ++ni) {
      int s_local = w * 32 + ni * 16 + lr;
      bool msk = mask[b * S + s0 + s_local];
#pragma unroll
      for (int mi = 0; mi < 2; ++mi) {
        int trow = mi * 16 + lg * 4;
#pragma unroll
        for (int rg = 0; rg < 4; ++rg) {
          float val = msk ? -INFINITY : acc[mi][ni][rg] * 0.125f;
          sc[(trow + rg) * SCP + s0 + s_local] = __float2bfloat16(val);
        }
      }
    }
    __syncthreads();
  }

  unsigned short* scu = (unsigned short*)sc;
  unsigned short* pgu = (unsigned short*)Pg;
#pragma unroll
  for (int i = 0; i < 8; ++i) {
    int r = w * 8 + i;
    float x[8];
    float m = -INFINITY;
#pragma unroll
    for (int j = 0; j < 8; ++j) {
      x[j] = b2f(scu[r * SCP + j * 64 + lane]);
      m = fmaxf(m, x[j]);
    }
#pragma unroll
    for (int o = 32; o > 0; o >>= 1) m = fmaxf(m, __shfl_xor(m, o));
    float ssum = 0.f;
#pragma unroll
    for (int j = 0; j < 8; ++j) { x[j] = __expf(x[j] - m); ssum += x[j]; }
#pragma unroll
    for (int o = 32; o > 0; o >>= 1) ssum += __shfl_xor(ssum, o);
    float inv = 1.f / ssum;
#pragma unroll
    for (int j = 0; j < 8; ++j) {
      unsigned short pb = f2b(x[j] * inv);
      scu[r * SCP + j * 64 + lane] = pb;
      pgu[(((size_t)(b * H + h)) * T + t0 + r) * S + j * 64 + lane] = pb;
    }
  }
  __syncthreads();

  f32x4 accp[2] = {};
  for (int ch = 0; ch < 4; ++ch) {
    const int s0 = ch * 128;
#pragma unroll
    for (int it = 0; it < 4; ++it) {
      int c = tid + it * 256;
      int d = c >> 4, slot = c & 15;
      int g = slot ^ (d & 7);
      async16(&vt[(((size_t)(b * H + h)) * 64 + d) * S + s0 + g * 8],
              (void*)&KVls[c * 8]);
    }
    __syncthreads();
#pragma unroll
    for (int ks = 0; ks < 4; ++ks) {
      bf16x8 bfr;
      {
        int brow = w * 16 + lr;
        int slot = (4 * ks + lg) ^ (brow & 7);
        bfr = *(const bf16x8*)&KVls[brow * 128 + slot * 8];
      }
#pragma unroll
      for (int mi = 0; mi < 2; ++mi) {
        int prow = mi * 16 + lr;
        bf16x8 af = *(const bf16x8*)&sc[prow * SCP + s0 + ks * 32 + lg * 8];
        accp[mi] = __builtin_amdgcn_mfma_f32_16x16x32_bf16(af, bfr, accp[mi], 0, 0, 0);
      }
    }
    __syncthreads();
  }
#pragma unroll
  for (int mi = 0; mi < 2; ++mi) {
    int trow = mi * 16 + lg * 4;
#pragma unroll
    for (int rg = 0; rg < 4; ++rg) {
      ctx[((size_t)(b * T + t0 + trow + rg)) * D + h * 64 + w * 16 + lr] =
          __float2bfloat16(accp[mi][rg]);
    }
  }
}

// ---------------------------------------------------------------------------
// Scatter v3: one block per (b,t) row. Computes its own copy gate (dot over
// ctx row) and ontology softmax (from split-K partials), then does the
// atomic scatter. Output rows pre-zeroed by gemm_mega's zero blocks.
// ---------------------------------------------------------------------------
__global__ __launch_bounds__(256) void scatter3_kernel(
    const int* __restrict__ src, const int* __restrict__ onto,
    const __hip_bfloat16* __restrict__ Pg, const float* __restrict__ part,
    const float* __restrict__ b2v, const __hip_bfloat16* __restrict__ ctx,
    const float* __restrict__ weff, float* __restrict__ out) {
  const int bt = blockIdx.x;           // B*T
  const int b = bt >> 8, t = bt & (T - 1);
  const int tid = threadIdx.x;
  const int lane = tid & 63;
  float* row = out + (size_t)bt * V;

  __shared__ float red[256];
  __shared__ float onts[O];

  // copy gate: dot(ctx[bt], weff) over D=768
  const unsigned short* cu = (const unsigned short*)ctx + (size_t)bt * D;
  float a = 0.f;
#pragma unroll
  for (int j = 0; j < 3; ++j) {
    int d = j * 256 + tid;
    a += b2f(cu[d]) * weff[d];
  }
  red[tid] = a;
  __syncthreads();
  for (int st = 128; st > 0; st >>= 1) {
    if (tid < st) red[tid] += red[tid + st];
    __syncthreads();
  }
  const float cpv = 1.f / (1.f + __expf(-(red[0] + weff[D])));
  __syncthreads();

  // ontology softmax (wave 0): reduce 16 partials + bias, softmax over 64
  if (tid < 64) {
    float x = b2v[lane];
#pragma unroll
    for (int sp = 0; sp < NSPLIT; ++sp)
      x += part[((size_t)sp * (B * T) + bt) * 64 + lane];
    float m = x;
#pragma unroll
    for (int o = 32; o > 0; o >>= 1) m = fmaxf(m, __shfl_xor(m, o));
    float e = __expf(x - m);
    float ss = e;
#pragma unroll
    for (int o = 32; o > 0; o >>= 1) ss += __shfl_xor(ss, o);
    onts[lane] = e / ss * (1.f - cpv);
  }
  __syncthreads();

  // source scatter (512 ids)
  const unsigned short* pg = (const unsigned short*)Pg;
#pragma unroll
  for (int jj = 0; jj < 2; ++jj) {
    int s = jj * 256 + tid;
    float sum = 0.f;
#pragma unroll
    for (int h = 0; h < H; ++h)
      sum += b2f(pg[(((size_t)(b * H + h)) * T + t) * S + s]);
    atomicAdd(&row[src[b * S + s]], sum * (1.0f / (float)H) * cpv);
  }
  // ontology (64 ids)
  if (tid < O) atomicAdd(&row[onto[tid]], onts[tid]);
}

// ---------------------------------------------------------------------------
extern "C" void kernel_launch(void* const* d_in, const int* in_sizes, int n_in,
                              void* d_out, int out_size, void* d_ws, size_t ws_size,
                              hipStream_t stream) {
  const int* src_ids = (const int*)d_in[0];
  const float* enc = (const float*)d_in[1];
  const unsigned char* mask = (const unsigned char*)d_in[2];
  const float* dec = (const float*)d_in[3];
  const int* onto_ids = (const int*)d_in[4];
  const float* Wq = (const float*)d_in[5];
  const float* bq = (const float*)d_in[6];
  const float* Wk = (const float*)d_in[7];
  const float* bk = (const float*)d_in[8];
  const float* Wv = (const float*)d_in[9];
  const float* bv = (const float*)d_in[10];
  const float* Wo = (const float*)d_in[11];
  const float* bo = (const float*)d_in[12];
  const float* copy_w = (const float*)d_in[13];
  const float* copy_b = (const float*)d_in[14];
  const float* W1 = (const float*)d_in[15];
  const float* b1 = (const float*)d_in[16];
  const float* W2 = (const float*)d_in[17];
  const float* b2 = (const float*)d_in[18];

  const int MT = B * T;   // 2048
  const int MS = B * S;   // 4096

  // bf16 workspace (persistent)
  __hip_bfloat16* wb = (__hip_bfloat16*)d_ws;
  __hip_bfloat16* qb16 = wb;    wb += (size_t)MT * D;
  __hip_bfloat16* kb16 = wb;    wb += (size_t)MS * D;
  __hip_bfloat16* vt = wb;      wb += (size_t)MS * D;        // [b][h][d][s]
  __hip_bfloat16* ctxb16 = wb;  wb += (size_t)MT * D;
  __hip_bfloat16* W2b = wb;     wb += (size_t)O * HID;
  __hip_bfloat16* WB = wb;      wb += (size_t)2 * D * D;     // [Wk; Wv]
  __hip_bfloat16* WA = wb;      wb += (size_t)(HID + D) * D; // [W1; Wq]
  // transient region aliased by Pg (decb/encb/hb16 dead before attention3)
  __hip_bfloat16* Pg = wb;
  __hip_bfloat16* decb = wb;
  __hip_bfloat16* encb = decb + (size_t)MT * D;
  __hip_bfloat16* hb16 = encb + (size_t)MS * D;
  wb += (size_t)B * H * T * S;  // 12.58M elems >= 11.01M transient
  // fp32 workspace
  float* wf = (float*)wb;
  float* part = wf;             wf += (size_t)NSPLIT * MT * O;  // split-K partials
  float* weff = wf;             wf += (size_t)(D + 1);

  float* out = (float*)d_out;

  // conversions + w_eff (one launch)
  cvt_weff_kernel<<<CH6 / 256 + 4, 256, 0, stream>>>(
      dec, enc, W1, Wq, Wk, Wv, W2, Wo, bo, copy_w, copy_b,
      decb, encb, WA, WB, W2b, weff);

  // merged K/V + FFN1/Q projections + output zeroing (2048 blocks)
  gemm_mega_kernel<<<GEMM_BLOCKS + ZERO_BLOCKS, 256, 0, stream>>>(
      encb, WB, bk, bv, kb16, vt, decb, WA, b1, bq, hb16, qb16, out);

  // FFN2 split-K (256 blocks)
  gemm_ffn2_kernel<<<dim3(NSPLIT, MT / 128), 256, 0, stream>>>(hb16, W2b, part);

  // attention (Pg alias region dead from here on)
  attention3_kernel<<<B * H * (T / 32), 256, 0, stream>>>(
      qb16, kb16, vt, mask, ctxb16, Pg);

  // fused copy-gate + ontology-softmax + scatter (one block per output row)
  scatter3_kernel<<<MT, 256, 0, stream>>>(
      src_ids, onto_ids, Pg, part, b2, ctxb16, weff, out);
}